// Round 1
// baseline (195.893 us; speedup 1.0000x reference)
//
#include <hip/hip_runtime.h>

// out[r] = sum_{s in ray r} w[s] * rgb[s,:]  (segment_ids sorted, fp32)
// Wave-autonomous, barrier-free, LDS-free.
// v2: 16 samples/lane (was 4). Each lane:
//   - issues all 20 dwordx4 loads upfront (4x MLP vs v1)
//   - sequential run-merge over its 16 sorted samples (interior runs rare ->
//     direct atomic flush; head/tail partials feed the cross-lane merge)
//   - one 6-step segmented shuffle scan per 1024-sample wave (4x fewer scans)
//   - one global atomicAdd triplet per run-end (out pre-zeroed)

#define NTHREADS 256
#define SPT 16  // samples per thread

__global__ __launch_bounds__(NTHREADS) void zero_out_kernel(float4* __restrict__ out4,
                                                            int n4) {
  int i = blockIdx.x * blockDim.x + threadIdx.x;
  if (i < n4) out4[i] = make_float4(0.f, 0.f, 0.f, 0.f);
}

__global__ __launch_bounds__(NTHREADS) void integrate_kernel(
    const int* __restrict__ ids, const float* __restrict__ rgb,
    const float* __restrict__ w, float* __restrict__ out, int n_samples) {
  const int lane = threadIdx.x & 63;
  const long long base = (long long)(blockIdx.x * blockDim.x + threadIdx.x) * SPT;

  int idv[SPT];
  float px[SPT], py[SPT], pz[SPT];

  if (base + (SPT - 1) < (long long)n_samples) {  // aligned fast path
    float ww[SPT], rr[3 * SPT];
    // all loads issued upfront; compile-time indices keep arrays in registers
    #pragma unroll
    for (int b = 0; b < SPT / 4; ++b) {
      const int4 t = *(const int4*)(ids + base + 4 * b);
      idv[4 * b + 0] = t.x; idv[4 * b + 1] = t.y;
      idv[4 * b + 2] = t.z; idv[4 * b + 3] = t.w;
    }
    #pragma unroll
    for (int b = 0; b < SPT / 4; ++b) {
      const float4 t = *(const float4*)(w + base + 4 * b);
      ww[4 * b + 0] = t.x; ww[4 * b + 1] = t.y;
      ww[4 * b + 2] = t.z; ww[4 * b + 3] = t.w;
    }
    #pragma unroll
    for (int m = 0; m < 3 * SPT / 4; ++m) {
      const float4 t = *(const float4*)(rgb + 3 * base + 4 * m);
      rr[4 * m + 0] = t.x; rr[4 * m + 1] = t.y;
      rr[4 * m + 2] = t.z; rr[4 * m + 3] = t.w;
    }
    #pragma unroll
    for (int k = 0; k < SPT; ++k) {
      px[k] = rr[3 * k + 0] * ww[k];
      py[k] = rr[3 * k + 1] * ww[k];
      pz[k] = rr[3 * k + 2] * ww[k];
    }
  } else {
    // Tail handling: pads replicate the last real id with zero contribution,
    // keeping all 64 lanes shuffle-active. Fully out-of-range lanes flush +0.
    const int last = ids[n_samples - 1];
    #pragma unroll
    for (int j = 0; j < SPT; ++j) {
      const long long s = base + j;
      if (s < n_samples) {
        idv[j] = ids[s];
        const float t = w[s];
        px[j] = rgb[3 * s + 0] * t;
        py[j] = rgb[3 * s + 1] * t;
        pz[j] = rgb[3 * s + 2] * t;
      } else {
        idv[j] = (j == 0) ? last : idv[j - 1];
        px[j] = py[j] = pz[j] = 0.f;
      }
    }
  }

  // ---- per-lane sequential run merge (ids sorted within lane) ------------
  const int first_id = idv[0];
  int run_id = first_id;
  float rx = px[0], ry = py[0], rz = pz[0];
  float hx = 0.f, hy = 0.f, hz = 0.f;
  bool f_intra = false;  // true once a run boundary occurred inside this lane
  #pragma unroll
  for (int k = 1; k < SPT; ++k) {
    if (idv[k] == run_id) {
      rx += px[k]; ry += py[k]; rz += pz[k];
    } else {
      if (!f_intra) {
        // first boundary: stash the head run for the cross-lane head flush
        hx = rx; hy = ry; hz = rz; f_intra = true;
      } else {
        // interior complete run (lane spans >=3 rays, rare) -> direct flush
        atomicAdd(&out[3 * run_id + 0], rx);
        atomicAdd(&out[3 * run_id + 1], ry);
        atomicAdd(&out[3 * run_id + 2], rz);
      }
      run_id = idv[k];
      rx = px[k]; ry = py[k]; rz = pz[k];
    }
  }
  const int last_id = run_id;  // tail run id (== idv[SPT-1])

  // ---- cross-lane segmented scan over tail partials ----------------------
  const int prev_tid = __shfl_up(last_id, 1, 64);  // tail id of lane-1
  int fl = (lane == 0 || f_intra || prev_tid != first_id) ? 1 : 0;
  float sx = rx, sy = ry, sz = rz;
  #pragma unroll
  for (int off = 1; off < 64; off <<= 1) {
    const float ox = __shfl_up(sx, off, 64);
    const float oy = __shfl_up(sy, off, 64);
    const float oz = __shfl_up(sz, off, 64);
    const int ofl = __shfl_up(fl, off, 64);
    if (lane >= off && fl == 0) { sx += ox; sy += oy; sz += oz; fl = ofl; }
  }

  // head-run flush: run ending inside this lane at the head prefix
  const float pSx = __shfl_up(sx, 1, 64);
  const float pSy = __shfl_up(sy, 1, 64);
  const float pSz = __shfl_up(sz, 1, 64);
  if (f_intra) {
    const bool link = (lane > 0) && (prev_tid == first_id);
    atomicAdd(&out[3 * first_id + 0], hx + (link ? pSx : 0.f));
    atomicAdd(&out[3 * first_id + 1], hy + (link ? pSy : 0.f));
    atomicAdd(&out[3 * first_id + 2], hz + (link ? pSz : 0.f));
  }

  // tail-run flush: last lane of each run within the wave
  const int next_hid = __shfl_down(first_id, 1, 64);  // head id of lane+1
  if (lane == 63 || next_hid != last_id) {
    atomicAdd(&out[3 * last_id + 0], sx);
    atomicAdd(&out[3 * last_id + 1], sy);
    atomicAdd(&out[3 * last_id + 2], sz);
  }
}

extern "C" void kernel_launch(void* const* d_in, const int* in_sizes, int n_in,
                              void* d_out, int out_size, void* d_ws, size_t ws_size,
                              hipStream_t stream) {
  const int*   segment_ids = (const int*)d_in[0];
  const float* rgb         = (const float*)d_in[1];
  const float* weights     = (const float*)d_in[2];
  float*       out         = (float*)d_out;

  const int n_samples = in_sizes[0];

  {  // zero output (all contributions arrive via atomics)
    int n4 = out_size / 4;  // out_size = n_rays*3*4B, divisible by 16
    int blocks = (n4 + NTHREADS - 1) / NTHREADS;
    zero_out_kernel<<<blocks, NTHREADS, 0, stream>>>((float4*)out, n4);
  }
  {
    int spb = NTHREADS * SPT;  // samples per block = 4096
    int blocks = (n_samples + spb - 1) / spb;
    integrate_kernel<<<blocks, NTHREADS, 0, stream>>>(
        segment_ids, rgb, weights, out, n_samples);
  }
}